// Round 19
// baseline (470.080 us; speedup 1.0000x reference)
//
#include <hip/hip_runtime.h>

using bf16u = unsigned short;
typedef __bf16 bf16x8 __attribute__((ext_vector_type(8)));
typedef float f32x4 __attribute__((ext_vector_type(4)));

#define DEV static __device__ __forceinline__

DEV float b2f(bf16u u) { return __uint_as_float(((unsigned int)u) << 16); }
DEV bf16u f2b(float f) {
  unsigned int x = __float_as_uint(f);
  unsigned int r = x + 0x7fffu + ((x >> 16) & 1u);  // RNE
  return (bf16u)(r >> 16);
}

DEV void gload16(const bf16u* g, bf16u* l) {
  __builtin_amdgcn_global_load_lds(
      (const __attribute__((address_space(1))) void*)g,
      (__attribute__((address_space(3))) void*)l, 16, 0, 0);
}

__global__ __launch_bounds__(64) void sentinel_k(float* o, float v) {
  if (threadIdx.x == 0) o[0] = v;
}

enum { EPI_QKV = 0, EPI_PV = 2, EPI_RESID = 3, EPI_RELU = 4, EPI_ACC = 5 };

struct GemmP {
  const bf16u* A; long lda, sA;
  const bf16u* Bt; long ldb, sB;
  int K;
  float scale;
  long sC;
  bf16u *q, *kk, *v;
  const float *bq, *bk, *bv;
  const float* biasf;
  const float* residf; long resid_row0;   // also: global head base for PV
  void* outp; long ldc;
};

// ---------------------------------------------------------------------------
// r18 core: 128x128, BK=64, double-buffered LDS, early STAGE + counted
// vmcnt(8) + raw barriers. Used for QKV / PV / Wo / MLP.
// ---------------------------------------------------------------------------
template <int EPI>
__global__ __launch_bounds__(256, 2) void gemm_db_k(GemmP p) {
  __shared__ __align__(16) bf16u As[2][8192];
  __shared__ __align__(16) bf16u Bs[2][8192];
  const int tid = threadIdx.x;
  const int lane = tid & 63;
  const int wid = tid >> 6;
  const int wr = wid >> 1, wc = wid & 1;

  const int gx = gridDim.x;
  const int nwg = gx * gridDim.y;
  const int lin = blockIdx.y * gx + blockIdx.x;
  const int chunk = nwg >> 3;
  const int swz = (nwg % 8 == 0) ? ((lin & 7) * chunk + (lin >> 3)) : lin;
  const int m0 = (swz / gx) << 7;
  const int n0 = (swz % gx) << 7;
  const int bz = blockIdx.z;

  const bf16u* A = p.A + (long)bz * p.sA;
  const bf16u* Bt = p.Bt + (long)bz * p.sB;

  f32x4 acc[4][4];
#pragma unroll
  for (int i = 0; i < 4; ++i)
#pragma unroll
    for (int j = 0; j < 4; ++j) acc[i][j] = {0.f, 0.f, 0.f, 0.f};

  const int r = tid >> 2;
  const int c8 = (tid & 3) << 3;
  const bf16u* ga0 = A + (long)(m0 + r) * p.lda + c8;
  const bf16u* ga1 = A + (long)(m0 + 64 + r) * p.lda + c8;
  const bf16u* gb0 = Bt + (long)(n0 + r) * p.ldb + c8;
  const bf16u* gb1 = Bt + (long)(n0 + 64 + r) * p.ldb + c8;

  const int lr = lane & 15;
  const int lk = (lane >> 4) << 3;
  const int NT = p.K >> 6;

#define STAGE(t_, b_)                                      \
  do {                                                     \
    const int ko = (t_) << 6;                              \
    gload16(ga0 + ko, &As[b_][tid * 8]);                   \
    gload16(ga1 + ko, &As[b_][2048 + tid * 8]);            \
    gload16(gb0 + ko, &Bs[b_][tid * 8]);                   \
    gload16(gb1 + ko, &Bs[b_][2048 + tid * 8]);            \
    gload16(ga0 + ko + 32, &As[b_][4096 + tid * 8]);       \
    gload16(ga1 + ko + 32, &As[b_][6144 + tid * 8]);       \
    gload16(gb0 + ko + 32, &Bs[b_][4096 + tid * 8]);       \
    gload16(gb1 + ko + 32, &Bs[b_][6144 + tid * 8]);       \
  } while (0)

  STAGE(0, 0);

  for (int t = 0; t < NT; ++t) {
    const int cur = t & 1;
    if (t + 1 < NT) {
      STAGE(t + 1, cur ^ 1);
      asm volatile("s_waitcnt vmcnt(8)" ::: "memory");
    } else {
      asm volatile("s_waitcnt vmcnt(0)" ::: "memory");
    }
    __builtin_amdgcn_s_barrier();
    asm volatile("" ::: "memory");

    {
      bf16x8 af[4], bfr[4];
#pragma unroll
      for (int i = 0; i < 4; ++i)
        af[i] = *reinterpret_cast<const bf16x8*>(&As[cur][(wr * 64 + i * 16 + lr) * 32 + lk]);
#pragma unroll
      for (int j = 0; j < 4; ++j)
        bfr[j] = *reinterpret_cast<const bf16x8*>(&Bs[cur][(wc * 64 + j * 16 + lr) * 32 + lk]);
      __builtin_amdgcn_s_setprio(1);
#pragma unroll
      for (int i = 0; i < 4; ++i)
#pragma unroll
        for (int j = 0; j < 4; ++j)
          acc[i][j] = __builtin_amdgcn_mfma_f32_16x16x32_bf16(af[i], bfr[j], acc[i][j], 0, 0, 0);
      __builtin_amdgcn_s_setprio(0);
    }
    {
      bf16x8 af[4], bfr[4];
#pragma unroll
      for (int i = 0; i < 4; ++i)
        af[i] = *reinterpret_cast<const bf16x8*>(&As[cur][4096 + (wr * 64 + i * 16 + lr) * 32 + lk]);
#pragma unroll
      for (int j = 0; j < 4; ++j)
        bfr[j] = *reinterpret_cast<const bf16x8*>(&Bs[cur][4096 + (wc * 64 + j * 16 + lr) * 32 + lk]);
      __builtin_amdgcn_s_setprio(1);
#pragma unroll
      for (int i = 0; i < 4; ++i)
#pragma unroll
        for (int j = 0; j < 4; ++j)
          acc[i][j] = __builtin_amdgcn_mfma_f32_16x16x32_bf16(af[i], bfr[j], acc[i][j], 0, 0, 0);
      __builtin_amdgcn_s_setprio(0);
    }
    __builtin_amdgcn_s_barrier();
    asm volatile("" ::: "memory");
  }
#undef STAGE

  const int rbase = m0 + wr * 64 + ((lane >> 4) << 2);
  const int cbase = n0 + wc * 64 + (lane & 15);
#pragma unroll
  for (int i = 0; i < 4; ++i) {
#pragma unroll
    for (int j = 0; j < 4; ++j) {
#pragma unroll
      for (int e = 0; e < 4; ++e) {
        const int row = rbase + i * 16 + e;
        const int col = cbase + j * 16;
        float v = acc[i][j][e];
        if constexpr (EPI == EPI_QKV) {
          const int which = col >> 10;
          const int cc = col & 1023;
          const float* bp = which == 0 ? p.bq : (which == 1 ? p.bk : p.bv);
          v += bp[cc];
          const int bl = row >> 9, l = row & 511;
          const int h = cc >> 8, hd = cc & 255;
          const int bh = bl * 4 + h;
          if (which == 2) {
            p.v[(((long)bh * 256 + hd) << 9) + l] = f2b(v);   // V^T (bh,hd,l)
          } else {
            bf16u* dst = which == 0 ? p.q : p.kk;
            dst[(((long)bh * 512 + l) << 8) + hd] = f2b(v);
          }
        } else if constexpr (EPI == EPI_PV) {
          const int bhg = (int)p.resid_row0 + bz;
          const int bl = bhg >> 2, h = bhg & 3;
          ((bf16u*)p.outp)[((long)(bl * 512 + row) << 10) + h * 256 + col] = f2b(v);
        } else if constexpr (EPI == EPI_RESID) {
          v += p.biasf[col] + p.residf[(p.resid_row0 + row) * p.ldc + col];
          ((float*)p.outp)[(long)row * p.ldc + col] = v;
        } else if constexpr (EPI == EPI_ACC) {
          float* op = (float*)p.outp + (long)row * p.ldc + col;
          *op = *op + v;
        } else {  // EPI_RELU
          v += p.biasf[col];
          ((bf16u*)p.outp)[(long)row * p.ldc + col] = f2b(fmaxf(v, 0.f));
        }
      }
    }
  }
}

// ---------------------------------------------------------------------------
// FUSED scores+softmax: one block per (64 q-rows, head). BM=64, BN=512,
// K=256 (BK=32, 8 single-buffered tiles). Softmax fully in-register on the
// f32 accumulator (more accurate than the old bf16 round-trip): scale, fwL
// bias on q-row 0, row-max (in-lane j reduce + shfl over the 16-lane col
// group + cross-wave LDS), exp in place, row-sum, one bf16 write to SC,
// f32 head-0 slice to out2, entropy for (b, h=0, q=0).
// ---------------------------------------------------------------------------
__global__ __launch_bounds__(256) void sc_sm_k(const bf16u* __restrict__ Q,
                                               const bf16u* __restrict__ K,
                                               const float* __restrict__ FWL,
                                               bf16u* __restrict__ SC,
                                               float* __restrict__ out2,
                                               float* __restrict__ ENT,
                                               int hf) {
  __shared__ __align__(16) bf16u Aq[64 * 32];
  __shared__ __align__(16) bf16u Bk[512 * 32];
  __shared__ float redA[2][64];
  __shared__ float redB[2][64];

  const int tid = threadIdx.x;
  const int lane = tid & 63;
  const int wid = tid >> 6;
  const int wr = wid >> 1, wc = wid & 1;
  const int mt = blockIdx.x;          // m-tile [0,8)
  const int bhl = blockIdx.y;         // local head [0,32)
  const int bh = hf * 32 + bhl;
  const int b = bh >> 2, h = bh & 3;

  const bf16u* Qh = Q + (long)bhl * 131072 + (long)mt * 64 * 256;
  const bf16u* Kh = K + (long)bhl * 131072;

  f32x4 acc[2][16];
#pragma unroll
  for (int i = 0; i < 2; ++i)
#pragma unroll
    for (int j = 0; j < 16; ++j) acc[i][j] = {0.f, 0.f, 0.f, 0.f};

  const int lr = lane & 15;
  const int lk = (lane >> 4) << 3;
  const int sr = tid >> 2, sc8 = (tid & 3) << 3;

  for (int t = 0; t < 8; ++t) {
    const int ko = t << 5;
    gload16(Qh + (long)sr * 256 + ko + sc8, Aq + tid * 8);
#pragma unroll
    for (int ii = 0; ii < 8; ++ii)
      gload16(Kh + (long)(ii * 64 + sr) * 256 + ko + sc8, Bk + ii * 2048 + tid * 8);
    asm volatile("s_waitcnt vmcnt(0)" ::: "memory");
    __syncthreads();

    bf16x8 af0 = *reinterpret_cast<const bf16x8*>(&Aq[(wr * 32 + lr) * 32 + lk]);
    bf16x8 af1 = *reinterpret_cast<const bf16x8*>(&Aq[(wr * 32 + 16 + lr) * 32 + lk]);
#pragma unroll
    for (int j = 0; j < 16; ++j) {
      bf16x8 bfj = *reinterpret_cast<const bf16x8*>(&Bk[(wc * 256 + j * 16 + lr) * 32 + lk]);
      acc[0][j] = __builtin_amdgcn_mfma_f32_16x16x32_bf16(af0, bfj, acc[0][j], 0, 0, 0);
      acc[1][j] = __builtin_amdgcn_mfma_f32_16x16x32_bf16(af1, bfj, acc[1][j], 0, 0, 0);
    }
    __syncthreads();
  }

  // scale + fwL bias (q-row 0 lives only in mt==0, wr==0, lane>>4==0, e==0)
#pragma unroll
  for (int i = 0; i < 2; ++i)
#pragma unroll
    for (int j = 0; j < 16; ++j)
#pragma unroll
      for (int e = 0; e < 4; ++e) acc[i][j][e] *= (1.f / 16.f);
  if (mt == 0 && wr == 0 && (lane >> 4) == 0) {
#pragma unroll
    for (int j = 0; j < 16; ++j)
      acc[0][j][0] += FWL[wc * 256 + j * 16 + lr] * 3.0f;  // BIAS_STRENGTH
  }

  const int rsub = (lane >> 4) << 2;
  // --- row max ---
  float mx[2][4];
#pragma unroll
  for (int i = 0; i < 2; ++i)
#pragma unroll
    for (int e = 0; e < 4; ++e) {
      float m = acc[i][0][e];
#pragma unroll
      for (int j = 1; j < 16; ++j) m = fmaxf(m, acc[i][j][e]);
#pragma unroll
      for (int o = 1; o <= 8; o <<= 1) m = fmaxf(m, __shfl_xor(m, o));
      mx[i][e] = m;
    }
  if (lr == 0) {
#pragma unroll
    for (int i = 0; i < 2; ++i)
#pragma unroll
      for (int e = 0; e < 4; ++e) redA[wc][wr * 32 + i * 16 + rsub + e] = mx[i][e];
  }
  __syncthreads();
#pragma unroll
  for (int i = 0; i < 2; ++i)
#pragma unroll
    for (int e = 0; e < 4; ++e)
      mx[i][e] = fmaxf(mx[i][e], redA[wc ^ 1][wr * 32 + i * 16 + rsub + e]);

  // --- exp in place + row sum ---
  float rs[2][4];
#pragma unroll
  for (int i = 0; i < 2; ++i)
#pragma unroll
    for (int e = 0; e < 4; ++e) {
      float ssum = 0.f;
#pragma unroll
      for (int j = 0; j < 16; ++j) {
        float pexp = __expf(acc[i][j][e] - mx[i][e]);
        acc[i][j][e] = pexp;
        ssum += pexp;
      }
#pragma unroll
      for (int o = 1; o <= 8; o <<= 1) ssum += __shfl_xor(ssum, o);
      rs[i][e] = ssum;
    }
  if (lr == 0) {
#pragma unroll
    for (int i = 0; i < 2; ++i)
#pragma unroll
      for (int e = 0; e < 4; ++e) redB[wc][wr * 32 + i * 16 + rsub + e] = rs[i][e];
  }
  __syncthreads();
#pragma unroll
  for (int i = 0; i < 2; ++i)
#pragma unroll
    for (int e = 0; e < 4; ++e)
      rs[i][e] = 1.f / (rs[i][e] + redB[wc ^ 1][wr * 32 + i * 16 + rsub + e]);

  // --- write attn (bf16 to SC; f32 head-0 slice) ---
#pragma unroll
  for (int i = 0; i < 2; ++i) {
#pragma unroll
    for (int e = 0; e < 4; ++e) {
      const int qrow = mt * 64 + wr * 32 + i * 16 + rsub + e;
      bf16u* dS = SC + ((long)bhl * 512 + qrow) * 512 + wc * 256 + lr;
      float* dO = out2 + ((long)b * 512 + qrow) * 512 + wc * 256 + lr;
#pragma unroll
      for (int j = 0; j < 16; ++j) {
        const float pp = acc[i][j][e] * rs[i][e];
        dS[j * 16] = f2b(pp);
        if (h == 0) dO[j * 16] = pp;
      }
    }
  }

  // --- entropy for (b, h==0, q==0) ---
  if (h == 0 && mt == 0) {
    float ep = 0.f;
    if (wr == 0 && (lane >> 4) == 0) {
#pragma unroll
      for (int j = 0; j < 16; ++j) {
        const float pp = acc[0][j][0] * rs[0][0];
        ep -= pp * logf(pp + 1e-8f);
      }
#pragma unroll
      for (int o = 1; o <= 8; o <<= 1) ep += __shfl_xor(ep, o);
    }
    __syncthreads();
    if (wr == 0 && (lane >> 4) == 0 && lr == 0) redA[wc][0] = ep;
    __syncthreads();
    if (tid == 0) ENT[b] = redA[0][0] + redA[1][0];
  }
}

// ---------------------------------------------------------------------------
__global__ __launch_bounds__(256) void ln_k(const float* __restrict__ x,
                                            bf16u* __restrict__ y,
                                            const float* __restrict__ g,
                                            const float* __restrict__ be,
                                            long row0, int affine) {
  const long row = row0 + blockIdx.x;
  const int tid = threadIdx.x;
  const float* xr = x + row * 1024;
  float4 u = *reinterpret_cast<const float4*>(xr + tid * 4);
  float xv[4] = {u.x, u.y, u.z, u.w};
  float s = xv[0] + xv[1] + xv[2] + xv[3];
  float s2 = xv[0] * xv[0] + xv[1] * xv[1] + xv[2] * xv[2] + xv[3] * xv[3];
#pragma unroll
  for (int o = 32; o; o >>= 1) {
    s += __shfl_down(s, o);
    s2 += __shfl_down(s2, o);
  }
  __shared__ float red[8];
  const int w = tid >> 6, lane = tid & 63;
  if (!lane) { red[w] = s; red[4 + w] = s2; }
  __syncthreads();
  s = red[0] + red[1] + red[2] + red[3];
  s2 = red[4] + red[5] + red[6] + red[7];
  const float mu = s * (1.f / 1024.f);
  const float var = s2 * (1.f / 1024.f) - mu * mu;
  const float inv = rsqrtf(var + 1e-5f);
  float o0 = (xv[0] - mu) * inv, o1 = (xv[1] - mu) * inv;
  float o2 = (xv[2] - mu) * inv, o3 = (xv[3] - mu) * inv;
  if (affine) {
    float4 ug = *reinterpret_cast<const float4*>(g + tid * 4);
    float4 ub = *reinterpret_cast<const float4*>(be + tid * 4);
    o0 = o0 * ug.x + ub.x; o1 = o1 * ug.y + ub.y;
    o2 = o2 * ug.z + ub.z; o3 = o3 * ug.w + ub.w;
  }
  ushort4 o4 = {f2b(o0), f2b(o1), f2b(o2), f2b(o3)};
  *reinterpret_cast<ushort4*>(y + (long)blockIdx.x * 1024 + tid * 4) = o4;
}

// ---------------------------------------------------------------------------
__global__ __launch_bounds__(256) void transpose_k(const float* __restrict__ in,
                                                   bf16u* __restrict__ out,
                                                   int M, int N) {
  __shared__ float t[32][33];
  const int n0 = blockIdx.x << 5, m0 = blockIdx.y << 5;
  const int tx = threadIdx.x & 31, ty = threadIdx.x >> 5;
#pragma unroll
  for (int yy = ty; yy < 32; yy += 8)
    t[yy][tx] = in[(long)(m0 + yy) * N + (n0 + tx)];
  __syncthreads();
#pragma unroll
  for (int yy = ty; yy < 32; yy += 8)
    out[(long)(n0 + yy) * M + (m0 + tx)] = f2b(t[tx][yy]);
}

// ---------------------------------------------------------------------------
__global__ __launch_bounds__(512) void fwl_k(const float* __restrict__ fw,
                                             const float* __restrict__ temp,
                                             const float* __restrict__ fs,
                                             float* __restrict__ FWL) {
  const int t = threadIdx.x;
  const float x = fw[t];
  __shared__ float red[16];
  float s = x;
#pragma unroll
  for (int o = 32; o; o >>= 1) s += __shfl_down(s, o);
  const int w = t >> 6, lane = t & 63;
  if (!lane) red[w] = s;
  __syncthreads();
  float tot = 0.f;
#pragma unroll
  for (int i = 0; i < 8; ++i) tot += red[i];
  const float mean = tot * (1.f / 512.f);
  const float d = x - mean;
  float sq = d * d;
#pragma unroll
  for (int o = 32; o; o >>= 1) sq += __shfl_down(sq, o);
  if (!lane) red[8 + w] = sq;
  __syncthreads();
  float tot2 = 0.f;
#pragma unroll
  for (int i = 0; i < 8; ++i) tot2 += red[8 + i];
  const float stdv = sqrtf(tot2 * (1.f / 511.f));  // ddof=1
  float val = x;
  if (stdv < 0.5f) val += (t < 5) ? 2.0f : -0.5f;
  val = val * fs[0] / temp[0];
  FWL[t] = val;
}

__global__ __launch_bounds__(512) void fixup_k(const float* __restrict__ ENT,
                                               bf16u* __restrict__ SCh,
                                               float* __restrict__ out2, int hf) {
  const int bl = blockIdx.x;
  const int b = hf * 8 + bl;
  const int k = threadIdx.x;
  if (!(ENT[b] > 0.9f * logf(512.f))) return;  // NaN-safe
  const float val = (k < 3) ? (0.7f / 3.f) : (0.3f / 509.f);
  SCh[((long)(bl * 4) << 18) + k] = f2b(val);
  out2[((long)b << 18) + k] = val;
}

// ---------------------------------------------------------------------------
extern "C" void kernel_launch(void* const* d_in, const int* in_sizes, int n_in,
                              void* d_out, int out_size, void* d_ws, size_t ws_size,
                              hipStream_t stream) {
  float* out0 = (float*)d_out;
  const size_t Mi = 1ull << 20;

  if (n_in != 19) { sentinel_k<<<1, 64, 0, stream>>>(out0, 60000.f); return; }
  if (out_size != 14680064 && out_size != 58720256) {
    sentinel_k<<<1, 64, 0, stream>>>(out0, 50000.f); return;
  }
  const size_t NEED = 64 * Mi;
  if (d_ws == nullptr || ws_size < NEED) {
    int m = (int)(ws_size >> 20); if (m > 127) m = 127;
    sentinel_k<<<1, 64, 0, stream>>>(out0, 4096.f * (float)(1 + m));
    return;
  }

  const float* s    = (const float*)d_in[0];
  const float* z    = (const float*)d_in[1];
  const float* wq   = (const float*)d_in[2];
  const float* bq   = (const float*)d_in[3];
  const float* wk   = (const float*)d_in[4];
  const float* bk   = (const float*)d_in[5];
  const float* wv   = (const float*)d_in[6];
  const float* bv   = (const float*)d_in[7];
  const float* wo   = (const float*)d_in[8];
  const float* bo   = (const float*)d_in[9];
  const float* fw   = (const float*)d_in[10];
  const float* temp = (const float*)d_in[11];
  const float* fs   = (const float*)d_in[12];
  const float* lng  = (const float*)d_in[13];
  const float* lnb  = (const float*)d_in[14];
  const float* w1   = (const float*)d_in[15];
  const float* b1   = (const float*)d_in[16];
  const float* w2   = (const float*)d_in[17];
  const float* b2   = (const float*)d_in[18];

  // ws (64 MiB), r18-proven layout:
  // Phase 1: [0,16) Qf (-> OUTf per half)  [16,32) Kf  [32,48) VTf
  //          [48,64) SCh per half; WTQ early at [48,54)
  // SLNf in out2p slice; WOT/FWL/ENT in z slice (overwritten by final z copy).
  // Phase 2: [0,8) W1T  [8,16) W2T  [16,32) Hf  [32,64) M1p half
  char* ws = (char*)d_ws;
  bf16u* Qf   = (bf16u*)(ws + 0 * Mi);
  bf16u* OUTf = Qf;
  bf16u* Kf   = (bf16u*)(ws + 16 * Mi);
  bf16u* VTf  = (bf16u*)(ws + 32 * Mi);
  bf16u* SCh  = (bf16u*)(ws + 48 * Mi);
  bf16u* WTQ  = (bf16u*)(ws + 48 * Mi);   // dead before first sc_sm
  bf16u* W1T  = (bf16u*)(ws + 0 * Mi);
  bf16u* W2T  = (bf16u*)(ws + 8 * Mi);
  bf16u* Hf   = (bf16u*)(ws + 16 * Mi);
  bf16u* M1p  = (bf16u*)(ws + 32 * Mi);

  float* outz  = out0 + 8388608;
  float* out2p = out0 + 10485760;
  float* FWL   = outz;                    // 512 f32 (z slice head)
  float* ENT   = outz + 1024;             // 16 f32
  bf16u* WOT   = (bf16u*)(outz + 2048);   // 2 MiB in z slice
  bf16u* SLNf  = (bf16u*)out2p;           // 16 MiB in attn slice

  const dim3 blk(256);

  fwl_k<<<1, 512, 0, stream>>>(fw, temp, fs, FWL);

  transpose_k<<<dim3(32, 32), blk, 0, stream>>>(wq, WTQ, 1024, 1024);
  transpose_k<<<dim3(32, 32), blk, 0, stream>>>(wk, WTQ + 1048576, 1024, 1024);
  transpose_k<<<dim3(32, 32), blk, 0, stream>>>(wv, WTQ + 2097152, 1024, 1024);
  transpose_k<<<dim3(32, 32), blk, 0, stream>>>(wo, WOT, 1024, 1024);

  ln_k<<<8192, blk, 0, stream>>>(s, SLNf, nullptr, nullptr, 0, 0);

  {  // QKV full: (8192x1024)@Bt(3072x1024)
    GemmP p{};
    p.A = SLNf; p.lda = 1024;
    p.Bt = WTQ; p.ldb = 1024;
    p.K = 1024;
    p.q = Qf; p.kk = Kf; p.v = VTf;
    p.bq = bq; p.bk = bk; p.bv = bv;
    gemm_db_k<EPI_QKV><<<dim3(24, 64, 1), blk, 0, stream>>>(p);
  }

  for (int hf = 0; hf < 2; ++hf) {
    const long hoff = (long)hf * 32 * 131072;
    // fused scores + softmax (writes SCh, out2p head-0 rows, ENT)
    sc_sm_k<<<dim3(8, 32), blk, 0, stream>>>(Qf + hoff, Kf + hoff, FWL,
                                             SCh, out2p, ENT, hf);
    fixup_k<<<8, 512, 0, stream>>>(ENT, SCh, out2p, hf);
    {  // PV
      GemmP p{};
      p.A = SCh; p.lda = 512; p.sA = 262144;
      p.Bt = VTf + hoff; p.ldb = 512; p.sB = 131072;
      p.K = 512; p.outp = OUTf; p.resid_row0 = hf * 32;
      gemm_db_k<EPI_PV><<<dim3(2, 4, 32), blk, 0, stream>>>(p);
    }
  }

  {  // s2 = s + OUT @ wo + bo
    GemmP p{};
    p.A = OUTf; p.lda = 1024;
    p.Bt = WOT; p.ldb = 1024;
    p.K = 1024;
    p.biasf = bo; p.residf = s; p.resid_row0 = 0;
    p.outp = out0; p.ldc = 1024;
    gemm_db_k<EPI_RESID><<<dim3(8, 64, 1), blk, 0, stream>>>(p);
  }

  transpose_k<<<dim3(128, 32), blk, 0, stream>>>(w1, W1T, 1024, 4096);
  transpose_k<<<dim3(32, 128), blk, 0, stream>>>(w2, W2T, 4096, 1024);

  ln_k<<<8192, blk, 0, stream>>>(out0, Hf, lng, lnb, 0, 1);

  for (int nc = 0; nc < 2; ++nc) {
    {  // M1p = relu(h @ w1[:, nc*2048:+2048] + b1)
      GemmP p{};
      p.A = Hf; p.lda = 1024;
      p.Bt = W1T + (long)nc * 2048 * 1024; p.ldb = 1024;
      p.K = 1024;
      p.biasf = b1 + nc * 2048; p.outp = M1p; p.ldc = 2048;
      gemm_db_k<EPI_RELU><<<dim3(16, 64, 1), blk, 0, stream>>>(p);
    }
    if (nc == 0) {
      GemmP p{};
      p.A = M1p; p.lda = 2048;
      p.Bt = W2T; p.ldb = 4096;
      p.K = 2048;
      p.biasf = b2; p.residf = out0; p.resid_row0 = 0;
      p.outp = out0; p.ldc = 1024;
      gemm_db_k<EPI_RESID><<<dim3(8, 64, 1), blk, 0, stream>>>(p);
    } else {
      GemmP p{};
      p.A = M1p; p.lda = 2048;
      p.Bt = W2T + 2048; p.ldb = 4096;
      p.K = 2048;
      p.outp = out0; p.ldc = 1024;
      gemm_db_k<EPI_ACC><<<dim3(8, 64, 1), blk, 0, stream>>>(p);
    }
  }

  // z passthrough (overwrites FWL/ENT/WOT scratch in z slice)
  hipMemcpyAsync(outz, z, (size_t)2097152 * 4, hipMemcpyDeviceToDevice, stream);
}

// Round 20
// 442.001 us; speedup vs baseline: 1.0635x; 1.0635x over previous
//
#include <hip/hip_runtime.h>

using bf16u = unsigned short;
typedef __bf16 bf16x8 __attribute__((ext_vector_type(8)));
typedef float f32x4 __attribute__((ext_vector_type(4)));

#define DEV static __device__ __forceinline__

DEV float b2f(bf16u u) { return __uint_as_float(((unsigned int)u) << 16); }
DEV bf16u f2b(float f) {
  unsigned int x = __float_as_uint(f);
  unsigned int r = x + 0x7fffu + ((x >> 16) & 1u);  // RNE
  return (bf16u)(r >> 16);
}

DEV void gload16(const bf16u* g, bf16u* l) {
  __builtin_amdgcn_global_load_lds(
      (const __attribute__((address_space(1))) void*)g,
      (__attribute__((address_space(3))) void*)l, 16, 0, 0);
}

__global__ __launch_bounds__(64) void sentinel_k(float* o, float v) {
  if (threadIdx.x == 0) o[0] = v;
}

enum { EPI_QKV = 0, EPI_SC = 1, EPI_PV = 2, EPI_RESID = 3, EPI_RELU = 4, EPI_ACC = 5 };

struct GemmP {
  const bf16u* A; long lda, sA;
  const bf16u* Bt; long ldb, sB;
  int K;
  float scale;
  long sC;
  bf16u *q, *kk, *v;
  const float *bq, *bk, *bv;
  const float* biasf;
  const float* residf; long resid_row0;   // also: global head base for PV
  void* outp; long ldc;
};

// ---------------------------------------------------------------------------
// r18 core: 128x128, BK=64, double-buffered LDS, early STAGE + counted
// vmcnt(8) + raw barriers. NEW: EPI_QKV uses an LDS-bounce epilogue so all
// Q/K/V^T writes are 256B-contiguous ushort4 runs (old V^T scatter was 2B
// stores at 1KB stride -- the QKV dispatch's write-side bottleneck).
// ---------------------------------------------------------------------------
template <int EPI>
__global__ __launch_bounds__(256, 2) void gemm_db_k(GemmP p) {
  __shared__ __align__(16) bf16u As[2][8192];
  __shared__ __align__(16) bf16u Bs[2][8192];
  const int tid = threadIdx.x;
  const int lane = tid & 63;
  const int wid = tid >> 6;
  const int wr = wid >> 1, wc = wid & 1;

  const int gx = gridDim.x;
  const int nwg = gx * gridDim.y;
  const int lin = blockIdx.y * gx + blockIdx.x;
  const int chunk = nwg >> 3;
  const int swz = (nwg % 8 == 0) ? ((lin & 7) * chunk + (lin >> 3)) : lin;
  const int m0 = (swz / gx) << 7;
  const int n0 = (swz % gx) << 7;
  const int bz = blockIdx.z;

  const bf16u* A = p.A + (long)bz * p.sA;
  const bf16u* Bt = p.Bt + (long)bz * p.sB;

  f32x4 acc[4][4];
#pragma unroll
  for (int i = 0; i < 4; ++i)
#pragma unroll
    for (int j = 0; j < 4; ++j) acc[i][j] = {0.f, 0.f, 0.f, 0.f};

  const int r = tid >> 2;
  const int c8 = (tid & 3) << 3;
  const bf16u* ga0 = A + (long)(m0 + r) * p.lda + c8;
  const bf16u* ga1 = A + (long)(m0 + 64 + r) * p.lda + c8;
  const bf16u* gb0 = Bt + (long)(n0 + r) * p.ldb + c8;
  const bf16u* gb1 = Bt + (long)(n0 + 64 + r) * p.ldb + c8;

  const int lr = lane & 15;
  const int lk = (lane >> 4) << 3;
  const int NT = p.K >> 6;

#define STAGE(t_, b_)                                      \
  do {                                                     \
    const int ko = (t_) << 6;                              \
    gload16(ga0 + ko, &As[b_][tid * 8]);                   \
    gload16(ga1 + ko, &As[b_][2048 + tid * 8]);            \
    gload16(gb0 + ko, &Bs[b_][tid * 8]);                   \
    gload16(gb1 + ko, &Bs[b_][2048 + tid * 8]);            \
    gload16(ga0 + ko + 32, &As[b_][4096 + tid * 8]);       \
    gload16(ga1 + ko + 32, &As[b_][6144 + tid * 8]);       \
    gload16(gb0 + ko + 32, &Bs[b_][4096 + tid * 8]);       \
    gload16(gb1 + ko + 32, &Bs[b_][6144 + tid * 8]);       \
  } while (0)

  STAGE(0, 0);

  for (int t = 0; t < NT; ++t) {
    const int cur = t & 1;
    if (t + 1 < NT) {
      STAGE(t + 1, cur ^ 1);
      asm volatile("s_waitcnt vmcnt(8)" ::: "memory");
    } else {
      asm volatile("s_waitcnt vmcnt(0)" ::: "memory");
    }
    __builtin_amdgcn_s_barrier();
    asm volatile("" ::: "memory");

    {
      bf16x8 af[4], bfr[4];
#pragma unroll
      for (int i = 0; i < 4; ++i)
        af[i] = *reinterpret_cast<const bf16x8*>(&As[cur][(wr * 64 + i * 16 + lr) * 32 + lk]);
#pragma unroll
      for (int j = 0; j < 4; ++j)
        bfr[j] = *reinterpret_cast<const bf16x8*>(&Bs[cur][(wc * 64 + j * 16 + lr) * 32 + lk]);
      __builtin_amdgcn_s_setprio(1);
#pragma unroll
      for (int i = 0; i < 4; ++i)
#pragma unroll
        for (int j = 0; j < 4; ++j)
          acc[i][j] = __builtin_amdgcn_mfma_f32_16x16x32_bf16(af[i], bfr[j], acc[i][j], 0, 0, 0);
      __builtin_amdgcn_s_setprio(0);
    }
    {
      bf16x8 af[4], bfr[4];
#pragma unroll
      for (int i = 0; i < 4; ++i)
        af[i] = *reinterpret_cast<const bf16x8*>(&As[cur][4096 + (wr * 64 + i * 16 + lr) * 32 + lk]);
#pragma unroll
      for (int j = 0; j < 4; ++j)
        bfr[j] = *reinterpret_cast<const bf16x8*>(&Bs[cur][4096 + (wc * 64 + j * 16 + lr) * 32 + lk]);
      __builtin_amdgcn_s_setprio(1);
#pragma unroll
      for (int i = 0; i < 4; ++i)
#pragma unroll
        for (int j = 0; j < 4; ++j)
          acc[i][j] = __builtin_amdgcn_mfma_f32_16x16x32_bf16(af[i], bfr[j], acc[i][j], 0, 0, 0);
      __builtin_amdgcn_s_setprio(0);
    }
    __builtin_amdgcn_s_barrier();
    asm volatile("" ::: "memory");
  }
#undef STAGE

  const int rbase = m0 + wr * 64 + ((lane >> 4) << 2);
  const int cbase = n0 + wc * 64 + (lane & 15);

  if constexpr (EPI == EPI_QKV) {
    // Tile-uniform mapping (m0,n0 multiples of 128; tiles never straddle a
    // head (256-col) or batch (512-row) boundary).
    const int which = n0 >> 10;             // 0:Q 1:K 2:V
    const int ccb = n0 & 1023;              // h*256 + hd0
    const int h = ccb >> 8;
    const int hd0 = ccb & 255;
    const int bl = m0 >> 9;
    const int l0 = m0 & 511;
    const int bh = bl * 4 + h;
    const float* bp = which == 0 ? p.bq : (which == 1 ? p.bk : p.bv);
    bf16u* T = (bf16u*)As;                  // 32KB: 128x128 bf16 bounce tile
    const int rloc = (rbase - m0);
    const int cloc = (cbase - n0);
#pragma unroll
    for (int i = 0; i < 4; ++i)
#pragma unroll
      for (int j = 0; j < 4; ++j)
#pragma unroll
        for (int e = 0; e < 4; ++e) {
          const int rl = rloc + i * 16 + e;
          const int cl = cloc + j * 16;
          const float v = acc[i][j][e] + bp[ccb + cl];
          if (which == 2) T[cl * 128 + rl] = f2b(v);   // [hd][l]
          else            T[rl * 128 + cl] = f2b(v);   // [l][hd]
        }
    __syncthreads();
    if (which == 2) {
      bf16u* dst = p.v + (((long)bh * 256 + hd0) << 9) + l0;
#pragma unroll
      for (int it = 0; it < 16; ++it) {
        const int hd_l = it * 8 + (tid >> 5);
        const int l_l = (tid & 31) * 4;
        *reinterpret_cast<ushort4*>(dst + ((long)hd_l << 9) + l_l) =
            *reinterpret_cast<const ushort4*>(&T[hd_l * 128 + l_l]);
      }
    } else {
      bf16u* dst = (which == 0 ? p.q : p.kk) + (((long)bh * 512 + l0) << 8) + hd0;
#pragma unroll
      for (int it = 0; it < 16; ++it) {
        const int l_l = it * 8 + (tid >> 5);
        const int hd_l = (tid & 31) * 4;
        *reinterpret_cast<ushort4*>(dst + ((long)l_l << 8) + hd_l) =
            *reinterpret_cast<const ushort4*>(&T[l_l * 128 + hd_l]);
      }
    }
    return;
  }

#pragma unroll
  for (int i = 0; i < 4; ++i) {
#pragma unroll
    for (int j = 0; j < 4; ++j) {
#pragma unroll
      for (int e = 0; e < 4; ++e) {
        const int row = rbase + i * 16 + e;
        const int col = cbase + j * 16;
        float v = acc[i][j][e];
        if constexpr (EPI == EPI_SC) {
          ((bf16u*)p.outp)[(long)bz * p.sC + (long)row * 512 + col] = f2b(v * p.scale);
        } else if constexpr (EPI == EPI_PV) {
          const int bhg = (int)p.resid_row0 + bz;
          const int bl = bhg >> 2, h = bhg & 3;
          ((bf16u*)p.outp)[((long)(bl * 512 + row) << 10) + h * 256 + col] = f2b(v);
        } else if constexpr (EPI == EPI_RESID) {
          v += p.biasf[col] + p.residf[(p.resid_row0 + row) * p.ldc + col];
          ((float*)p.outp)[(long)row * p.ldc + col] = v;
        } else if constexpr (EPI == EPI_ACC) {
          float* op = (float*)p.outp + (long)row * p.ldc + col;
          *op = *op + v;
        } else {  // EPI_RELU
          v += p.biasf[col];
          ((bf16u*)p.outp)[(long)row * p.ldc + col] = f2b(fmaxf(v, 0.f));
        }
      }
    }
  }
}

// ---------------------------------------------------------------------------
__global__ __launch_bounds__(256) void ln_k(const float* __restrict__ x,
                                            bf16u* __restrict__ y,
                                            const float* __restrict__ g,
                                            const float* __restrict__ be,
                                            long row0, int affine) {
  const long row = row0 + blockIdx.x;
  const int tid = threadIdx.x;
  const float* xr = x + row * 1024;
  float4 u = *reinterpret_cast<const float4*>(xr + tid * 4);
  float xv[4] = {u.x, u.y, u.z, u.w};
  float s = xv[0] + xv[1] + xv[2] + xv[3];
  float s2 = xv[0] * xv[0] + xv[1] * xv[1] + xv[2] * xv[2] + xv[3] * xv[3];
#pragma unroll
  for (int o = 32; o; o >>= 1) {
    s += __shfl_down(s, o);
    s2 += __shfl_down(s2, o);
  }
  __shared__ float red[8];
  const int w = tid >> 6, lane = tid & 63;
  if (!lane) { red[w] = s; red[4 + w] = s2; }
  __syncthreads();
  s = red[0] + red[1] + red[2] + red[3];
  s2 = red[4] + red[5] + red[6] + red[7];
  const float mu = s * (1.f / 1024.f);
  const float var = s2 * (1.f / 1024.f) - mu * mu;
  const float inv = rsqrtf(var + 1e-5f);
  float o0 = (xv[0] - mu) * inv, o1 = (xv[1] - mu) * inv;
  float o2 = (xv[2] - mu) * inv, o3 = (xv[3] - mu) * inv;
  if (affine) {
    float4 ug = *reinterpret_cast<const float4*>(g + tid * 4);
    float4 ub = *reinterpret_cast<const float4*>(be + tid * 4);
    o0 = o0 * ug.x + ub.x; o1 = o1 * ug.y + ub.y;
    o2 = o2 * ug.z + ub.z; o3 = o3 * ug.w + ub.w;
  }
  ushort4 o4 = {f2b(o0), f2b(o1), f2b(o2), f2b(o3)};
  *reinterpret_cast<ushort4*>(y + (long)blockIdx.x * 1024 + tid * 4) = o4;
}

// ---------------------------------------------------------------------------
__global__ __launch_bounds__(256) void transpose_k(const float* __restrict__ in,
                                                   bf16u* __restrict__ out,
                                                   int M, int N) {
  __shared__ float t[32][33];
  const int n0 = blockIdx.x << 5, m0 = blockIdx.y << 5;
  const int tx = threadIdx.x & 31, ty = threadIdx.x >> 5;
#pragma unroll
  for (int yy = ty; yy < 32; yy += 8)
    t[yy][tx] = in[(long)(m0 + yy) * N + (n0 + tx)];
  __syncthreads();
#pragma unroll
  for (int yy = ty; yy < 32; yy += 8)
    out[(long)(n0 + yy) * M + (m0 + tx)] = f2b(t[tx][yy]);
}

// ---------------------------------------------------------------------------
__global__ __launch_bounds__(512) void fwl_k(const float* __restrict__ fw,
                                             const float* __restrict__ temp,
                                             const float* __restrict__ fs,
                                             float* __restrict__ FWL) {
  const int t = threadIdx.x;
  const float x = fw[t];
  __shared__ float red[16];
  float s = x;
#pragma unroll
  for (int o = 32; o; o >>= 1) s += __shfl_down(s, o);
  const int w = t >> 6, lane = t & 63;
  if (!lane) red[w] = s;
  __syncthreads();
  float tot = 0.f;
#pragma unroll
  for (int i = 0; i < 8; ++i) tot += red[i];
  const float mean = tot * (1.f / 512.f);
  const float d = x - mean;
  float sq = d * d;
#pragma unroll
  for (int o = 32; o; o >>= 1) sq += __shfl_down(sq, o);
  if (!lane) red[8 + w] = sq;
  __syncthreads();
  float tot2 = 0.f;
#pragma unroll
  for (int i = 0; i < 8; ++i) tot2 += red[8 + i];
  const float stdv = sqrtf(tot2 * (1.f / 511.f));  // ddof=1
  float val = x;
  if (stdv < 0.5f) val += (t < 5) ? 2.0f : -0.5f;
  val = val * fs[0] / temp[0];
  FWL[t] = val;
}

// ---------------------------------------------------------------------------
__global__ __launch_bounds__(256) void softmax_k(bf16u* __restrict__ SC,
                                                 const float* __restrict__ FWL,
                                                 float* __restrict__ out2,
                                                 float* __restrict__ ENT,
                                                 int hf) {
  const int tid = threadIdx.x;
  const int w = tid >> 6, lane = tid & 63;
  const int rowid = blockIdx.x * 4 + w;
  const int bhl = rowid >> 9;
  const int qq = rowid & 511;
  const int bh = hf * 32 + bhl;
  const int b = bh >> 2, h = bh & 3;
  bf16u* src = SC + ((long)bhl * 512 + qq) * 512 + lane * 8;
  ushort4 u0 = *reinterpret_cast<const ushort4*>(src);
  ushort4 u1 = *reinterpret_cast<const ushort4*>(src + 4);
  float v[8] = {b2f(u0.x), b2f(u0.y), b2f(u0.z), b2f(u0.w),
                b2f(u1.x), b2f(u1.y), b2f(u1.z), b2f(u1.w)};
  if (qq == 0) {
#pragma unroll
    for (int e = 0; e < 8; ++e) v[e] += FWL[lane * 8 + e] * 3.0f;  // BIAS_STRENGTH
  }
  float mx = v[0];
#pragma unroll
  for (int e = 1; e < 8; ++e) mx = fmaxf(mx, v[e]);
#pragma unroll
  for (int o = 32; o; o >>= 1) mx = fmaxf(mx, __shfl_xor(mx, o));
  float sum = 0.f;
#pragma unroll
  for (int e = 0; e < 8; ++e) { v[e] = __expf(v[e] - mx); sum += v[e]; }
#pragma unroll
  for (int o = 32; o; o >>= 1) sum += __shfl_xor(sum, o);
  const float rs = 1.f / sum;
  float a[8];
#pragma unroll
  for (int e = 0; e < 8; ++e) a[e] = v[e] * rs;
  ushort4 lo = {f2b(a[0]), f2b(a[1]), f2b(a[2]), f2b(a[3])};
  ushort4 hi = {f2b(a[4]), f2b(a[5]), f2b(a[6]), f2b(a[7])};
  *reinterpret_cast<ushort4*>(src) = lo;
  *reinterpret_cast<ushort4*>(src + 4) = hi;
  if (h == 0) {
    float* dO = out2 + ((long)b * 512 + qq) * 512 + lane * 8;
    *reinterpret_cast<float4*>(dO) = make_float4(a[0], a[1], a[2], a[3]);
    *reinterpret_cast<float4*>(dO + 4) = make_float4(a[4], a[5], a[6], a[7]);
    if (qq == 0) {
      float ep = 0.f;
#pragma unroll
      for (int e = 0; e < 8; ++e) ep -= a[e] * logf(a[e] + 1e-8f);
#pragma unroll
      for (int o = 32; o; o >>= 1) ep += __shfl_xor(ep, o);
      if (!lane) ENT[b] = ep;
    }
  }
}

__global__ __launch_bounds__(512) void fixup_k(const float* __restrict__ ENT,
                                               bf16u* __restrict__ SCh,
                                               float* __restrict__ out2, int hf) {
  const int bl = blockIdx.x;
  const int b = hf * 8 + bl;
  const int k = threadIdx.x;
  if (!(ENT[b] > 0.9f * logf(512.f))) return;  // NaN-safe
  const float val = (k < 3) ? (0.7f / 3.f) : (0.3f / 509.f);
  SCh[((long)(bl * 4) << 18) + k] = f2b(val);
  out2[((long)b << 18) + k] = val;
}

// ---------------------------------------------------------------------------
extern "C" void kernel_launch(void* const* d_in, const int* in_sizes, int n_in,
                              void* d_out, int out_size, void* d_ws, size_t ws_size,
                              hipStream_t stream) {
  float* out0 = (float*)d_out;
  const size_t Mi = 1ull << 20;

  if (n_in != 19) { sentinel_k<<<1, 64, 0, stream>>>(out0, 60000.f); return; }
  if (out_size != 14680064 && out_size != 58720256) {
    sentinel_k<<<1, 64, 0, stream>>>(out0, 50000.f); return;
  }
  const size_t NEED = 64 * Mi;
  if (d_ws == nullptr || ws_size < NEED) {
    int m = (int)(ws_size >> 20); if (m > 127) m = 127;
    sentinel_k<<<1, 64, 0, stream>>>(out0, 4096.f * (float)(1 + m));
    return;
  }

  const float* s    = (const float*)d_in[0];
  const float* z    = (const float*)d_in[1];
  const float* wq   = (const float*)d_in[2];
  const float* bq   = (const float*)d_in[3];
  const float* wk   = (const float*)d_in[4];
  const float* bk   = (const float*)d_in[5];
  const float* wv   = (const float*)d_in[6];
  const float* bv   = (const float*)d_in[7];
  const float* wo   = (const float*)d_in[8];
  const float* bo   = (const float*)d_in[9];
  const float* fw   = (const float*)d_in[10];
  const float* temp = (const float*)d_in[11];
  const float* fs   = (const float*)d_in[12];
  const float* lng  = (const float*)d_in[13];
  const float* lnb  = (const float*)d_in[14];
  const float* w1   = (const float*)d_in[15];
  const float* b1   = (const float*)d_in[16];
  const float* w2   = (const float*)d_in[17];
  const float* b2   = (const float*)d_in[18];

  // ws (64 MiB), r18-proven layout:
  // Phase 1: [0,16) Qf (-> OUTf per half)  [16,32) Kf  [32,48) VTf
  //          [48,64) SCh per half; WTQ early at [48,54)
  // SLNf in out2p slice; WOT/FWL/ENT in z slice (overwritten by final z copy).
  // Phase 2: [0,8) W1T  [8,16) W2T  [16,32) Hf  [32,64) M1p half
  char* ws = (char*)d_ws;
  bf16u* Qf   = (bf16u*)(ws + 0 * Mi);
  bf16u* OUTf = Qf;
  bf16u* Kf   = (bf16u*)(ws + 16 * Mi);
  bf16u* VTf  = (bf16u*)(ws + 32 * Mi);
  bf16u* SCh  = (bf16u*)(ws + 48 * Mi);
  bf16u* WTQ  = (bf16u*)(ws + 48 * Mi);   // dead before first SC
  bf16u* W1T  = (bf16u*)(ws + 0 * Mi);
  bf16u* W2T  = (bf16u*)(ws + 8 * Mi);
  bf16u* Hf   = (bf16u*)(ws + 16 * Mi);
  bf16u* M1p  = (bf16u*)(ws + 32 * Mi);

  float* outz  = out0 + 8388608;
  float* out2p = out0 + 10485760;
  float* FWL   = outz;                    // 512 f32 (z slice head)
  float* ENT   = outz + 1024;             // 16 f32
  bf16u* WOT   = (bf16u*)(outz + 2048);   // 2 MiB in z slice
  bf16u* SLNf  = (bf16u*)out2p;           // 16 MiB in attn slice

  const dim3 blk(256);

  fwl_k<<<1, 512, 0, stream>>>(fw, temp, fs, FWL);

  transpose_k<<<dim3(32, 32), blk, 0, stream>>>(wq, WTQ, 1024, 1024);
  transpose_k<<<dim3(32, 32), blk, 0, stream>>>(wk, WTQ + 1048576, 1024, 1024);
  transpose_k<<<dim3(32, 32), blk, 0, stream>>>(wv, WTQ + 2097152, 1024, 1024);
  transpose_k<<<dim3(32, 32), blk, 0, stream>>>(wo, WOT, 1024, 1024);

  ln_k<<<8192, blk, 0, stream>>>(s, SLNf, nullptr, nullptr, 0, 0);

  {  // QKV full: (8192x1024)@Bt(3072x1024), coalesced bounce epilogue
    GemmP p{};
    p.A = SLNf; p.lda = 1024;
    p.Bt = WTQ; p.ldb = 1024;
    p.K = 1024;
    p.q = Qf; p.kk = Kf; p.v = VTf;
    p.bq = bq; p.bk = bk; p.bv = bv;
    gemm_db_k<EPI_QKV><<<dim3(24, 64, 1), blk, 0, stream>>>(p);
  }

  for (int hf = 0; hf < 2; ++hf) {
    const long hoff = (long)hf * 32 * 131072;
    {
      GemmP p{};
      p.A = Qf + hoff; p.lda = 256; p.sA = 131072;
      p.Bt = Kf + hoff; p.ldb = 256; p.sB = 131072;
      p.K = 256; p.outp = SCh; p.sC = 262144; p.scale = 1.f / 16.f;
      gemm_db_k<EPI_SC><<<dim3(4, 4, 32), blk, 0, stream>>>(p);
    }
    softmax_k<<<4096, blk, 0, stream>>>(SCh, FWL, out2p, ENT, hf);
    fixup_k<<<8, 512, 0, stream>>>(ENT, SCh, out2p, hf);
    {
      GemmP p{};
      p.A = SCh; p.lda = 512; p.sA = 262144;
      p.Bt = VTf + hoff; p.ldb = 512; p.sB = 131072;
      p.K = 512; p.outp = OUTf; p.resid_row0 = hf * 32;
      gemm_db_k<EPI_PV><<<dim3(2, 4, 32), blk, 0, stream>>>(p);
    }
  }

  {  // s2 = s + OUT @ wo + bo
    GemmP p{};
    p.A = OUTf; p.lda = 1024;
    p.Bt = WOT; p.ldb = 1024;
    p.K = 1024;
    p.biasf = bo; p.residf = s; p.resid_row0 = 0;
    p.outp = out0; p.ldc = 1024;
    gemm_db_k<EPI_RESID><<<dim3(8, 64, 1), blk, 0, stream>>>(p);
  }

  transpose_k<<<dim3(128, 32), blk, 0, stream>>>(w1, W1T, 1024, 4096);
  transpose_k<<<dim3(32, 128), blk, 0, stream>>>(w2, W2T, 4096, 1024);

  ln_k<<<8192, blk, 0, stream>>>(out0, Hf, lng, lnb, 0, 1);

  for (int nc = 0; nc < 2; ++nc) {
    {  // M1p = relu(h @ w1[:, nc*2048:+2048] + b1)
      GemmP p{};
      p.A = Hf; p.lda = 1024;
      p.Bt = W1T + (long)nc * 2048 * 1024; p.ldb = 1024;
      p.K = 1024;
      p.biasf = b1 + nc * 2048; p.outp = M1p; p.ldc = 2048;
      gemm_db_k<EPI_RELU><<<dim3(16, 64, 1), blk, 0, stream>>>(p);
    }
    if (nc == 0) {
      GemmP p{};
      p.A = M1p; p.lda = 2048;
      p.Bt = W2T; p.ldb = 4096;
      p.K = 2048;
      p.biasf = b2; p.residf = out0; p.resid_row0 = 0;
      p.outp = out0; p.ldc = 1024;
      gemm_db_k<EPI_RESID><<<dim3(8, 64, 1), blk, 0, stream>>>(p);
    } else {
      GemmP p{};
      p.A = M1p; p.lda = 2048;
      p.Bt = W2T + 2048; p.ldb = 4096;
      p.K = 2048;
      p.outp = out0; p.ldc = 1024;
      gemm_db_k<EPI_ACC><<<dim3(8, 64, 1), blk, 0, stream>>>(p);
    }
  }

  // z passthrough (overwrites FWL/ENT/WOT scratch in z slice)
  hipMemcpyAsync(outz, z, (size_t)2097152 * 4, hipMemcpyDeviceToDevice, stream);
}